// Round 7
// baseline (343.701 us; speedup 1.0000x reference)
//
#include <hip/hip_runtime.h>

typedef __attribute__((ext_vector_type(8))) short bf16x8;
typedef __attribute__((ext_vector_type(4))) float f32x4;
typedef __attribute__((ext_vector_type(4), aligned(4))) float f32x4u;  // 4B-aligned global loads
typedef __attribute__((ext_vector_type(4))) unsigned int u32x4;

#define BB 1024
#define TT 256
#define DD 63
#define HH 128
#define CHUNK 4    // 4 batch rows/block, grid 256 = 1 block/CU
#define HSTR 160   // shorts; 80 dwords ≡ 16 (mod 32): broadcast b128 reads exactly 2-way (free)

// Barrier that drains only LDS (lgkmcnt), NOT outstanding global loads.
#define LDS_BARRIER() asm volatile("s_waitcnt lgkmcnt(0)\n\ts_barrier" ::: "memory")

__device__ __forceinline__ short f2bf(float f) {
  unsigned u = __builtin_bit_cast(unsigned, f);
  u = (u + 0x7FFFu + ((u >> 16) & 1u)) >> 16;   // RNE
  return (short)u;
}
__device__ __forceinline__ unsigned cvtpk(float lo, float hi) {
  unsigned d;
  asm("v_cvt_pk_bf16_f32 %0, %1, %2" : "=v"(d) : "v"(lo), "v"(hi));  // RNE, = f2bf pair
  return d;
}
__device__ __forceinline__ float sigm(float x) {
  return __builtin_amdgcn_rcpf(1.f + __expf(-x));
}
__device__ __forceinline__ float tanh_fast(float x) {
  float e = __expf(2.f * x);
  return 1.f - 2.f * __builtin_amdgcn_rcpf(e + 1.f);
}

// R17 = R11 t-loop with the x OPERAND MOVED OFF THE LDS PIPE:
//   Unified post-mortem of R11/R14/R15/R16: step = MFMA-issue floor (931
//   cyc/SIMD, tracks MFMA count in EVERY round) + post-barrier LDS burst
//   (8 waves x 6 ds_read_b128 ~ 580 cyc/CU, serial with MFMA) + VALU tail.
//   R14 (+xp C-init reads, 8-way conflicts) and R16 (+16 bpermutes = same
//   LDS pipe) both ADDED LDS ops and lost; R15 changed neither pipe -> null.
//   The lever is LDS OP COUNT.
//   - Bx fragments now come from GLOBAL (16 contiguous floats of X[b][t]),
//     loaded one step ahead into VGPRs (full-step vmcnt slack across the
//     lgkm-only barrier; L1-resident: 1 KB/step shared by all waves),
//     converted by 8 v_cvt_pk_bf16_f32 (RNE = f2bf, bit-identical).
//   - Removes per step: 16 of 48 wave ds_read_b128 (-33% of the LDS burst),
//     all x ds_writes + the 252-thread staging machinery + xbuf.
//   - cc/tanh(cc) hoisted under the o-gate chain (tail shave).
// Chains/accumulation order identical to R11 -> absmax must stay 0.001953.
// Kept: launch_bounds(512,2) (R4); grid=256 = 1 block/CU (R5); HSTR=160
// (R7); one lgkm-only barrier/step (R8); per-gate stagger (R10); fused
// epilogue (R11).
__global__ __launch_bounds__(512, 2)
void bilstm_fused_kernel(const float* __restrict__ X,
                         const float* __restrict__ Wih,
                         const float* __restrict__ Whh,
                         const float* __restrict__ bih,
                         const float* __restrict__ bhh,
                         const float* __restrict__ Wih_b,
                         const float* __restrict__ bih_b,
                         const float* __restrict__ bhh_b,
                         const float* __restrict__ Wfc,
                         const float* __restrict__ bfc,
                         float* __restrict__ out) {
  __shared__ __align__(16) short hbuf[2 * 4 * HSTR];   // h^T (bf16), rows=batch 0..3, dbuf
  __shared__ __align__(16) float fst[4 * 256];         // epilogue [h_f ; h_b] per batch
  __shared__ __align__(16) float xl[4 * 64];           // x_last fp32, pad 64
  __shared__ __align__(16) float glb[4 * 512];         // bwd gate pre-acts [b][n]

  const int tid  = threadIdx.x;
  const int wave = tid >> 6;
  const int lane = tid & 63;
  const int quad = lane >> 4;
  const int l15  = lane & 15;
  const int b0   = blockIdx.x * CHUNK;
  const int br   = l15 & 3;        // this lane's batch row
  // duplicate-group index p = l15>>2 selects which acc register is valid

  // ---- register-resident W fragments as MFMA A operands ----
  bf16x8 Ah[4][4];   // [gate][kstep], W_hh
  bf16x8 Axw[4][2];  // [gate][kstep], W_ih (K padded 63->64)
  f32x4  bias[4];    // bias per acc reg q: col = wave*16 + quad*4 + q
#pragma unroll
  for (int g = 0; g < 4; ++g) {
    const int n = g * 128 + wave * 16 + l15;
    const float* wr = Whh + (size_t)n * HH;
#pragma unroll
    for (int ks = 0; ks < 4; ++ks) {
      const int k0 = ks * 32 + quad * 8;
      f32x4 w0 = *(const f32x4*)(wr + k0);
      f32x4 w1 = *(const f32x4*)(wr + k0 + 4);
      bf16x8 v;
#pragma unroll
      for (int jj = 0; jj < 4; ++jj) { v[jj] = f2bf(w0[jj]); v[4 + jj] = f2bf(w1[jj]); }
      Ah[g][ks] = v;
    }
    const float* xr = Wih + (size_t)n * DD;
#pragma unroll
    for (int ks = 0; ks < 2; ++ks) {
      const int k0 = ks * 32 + quad * 8;
      bf16x8 v;
#pragma unroll
      for (int jj = 0; jj < 8; ++jj) {
        const int k = k0 + jj;
        v[jj] = (k < DD) ? f2bf(xr[k]) : (short)0;
      }
      Axw[g][ks] = v;
    }
    const int cb = g * 128 + wave * 16 + quad * 4;
    f32x4 b1 = *(const f32x4*)&bih[cb];
    f32x4 b2 = *(const f32x4*)&bhh[cb];
    bias[g] = b1 + b2;
  }

  // zero h buffers (h(0)=0)
  for (int i = tid; i < 2 * 4 * HSTR; i += 512) hbuf[i] = 0;

  // ---- direct-from-global x operand: this lane's 16 floats of X[b0+br][t]
  // slice0 = k quad*8..+7, slice1 = k 32+quad*8..+7 (k=63 zeroed via kmask)
  const float* xbase = X + (size_t)(b0 + br) * TT * DD;
  const unsigned kmask = (quad == 3) ? 0x0000FFFFu : 0xFFFFFFFFu;
  const int xk0 = quad * 8;
  const int xk1 = 32 + quad * 8;
  // pending x(t) registers (issued one step ahead; dup lanes share addresses -> L1 broadcast)
  f32x4 pa, pb, pc, pd;
  {
    const float* r = xbase;                 // t = 0
    pa = *(const f32x4u*)(r + xk0);
    pb = *(const f32x4u*)(r + xk0 + 4);
    pc = *(const f32x4u*)(r + xk1);
    pd = *(const f32x4u*)(r + xk1 + 4);
  }
  __syncthreads();

  float cc = 0.f, hv = 0.f;   // ONE element per lane: (batch=br, col=wave*16+quad*4+p)
  const int hcol = wave * 16 + quad * 4 + (l15 >> 2);
  const bool s0 = (l15 & 4) != 0;
  const bool s1 = (l15 & 8) != 0;

  for (int t = 0; t < TT; ++t) {
    const int hcur = (t & 1) * (4 * HSTR);

    // h B-fragments: row br -> 4-way same-address broadcast, 2-way banks.
    // These 4 reads are now the ONLY per-step LDS reads.
    bf16x8 Bh_[4];
#pragma unroll
    for (int ks = 0; ks < 4; ++ks)
      Bh_[ks] = *(const bf16x8*)&hbuf[hcur + br * HSTR + ks * 32 + quad * 8];

    // convert pending x(t) -> Bx fragments (8 cvt_pk, RNE); then reissue
    // the pending regs with x(t+1) (clamped; stays in flight across the
    // lgkm-only barrier with a full step of slack)
    bf16x8 Bx0, Bx1;
    {
      u32x4 w;
      w[0] = cvtpk(pa[0], pa[1]); w[1] = cvtpk(pa[2], pa[3]);
      w[2] = cvtpk(pb[0], pb[1]); w[3] = cvtpk(pb[2], pb[3]);
      Bx0 = __builtin_bit_cast(bf16x8, w);
      w[0] = cvtpk(pc[0], pc[1]); w[1] = cvtpk(pc[2], pc[3]);
      w[2] = cvtpk(pd[0], pd[1]); w[3] = cvtpk(pd[2], pd[3]) & kmask;
      Bx1 = __builtin_bit_cast(bf16x8, w);
    }
    {
      const int tn = (t + 1 < TT) ? (t + 1) : (TT - 1);
      const float* r = xbase + (size_t)tn * DD;
      pa = *(const f32x4u*)(r + xk0);
      pb = *(const f32x4u*)(r + xk0 + 4);
      pc = *(const f32x4u*)(r + xk1);
      pd = *(const f32x4u*)(r + xk1 + 4);
    }

    // ---- per-gate staggered: 6-MFMA dependent chain, then THAT gate's
    //      select+activation; cc/tanh(cc) hoisted under the o-gate chain ----
    float gact[4];
    float tcc = 0.f;
#pragma unroll
    for (int g = 0; g < 4; ++g) {
      f32x4 a = __builtin_amdgcn_mfma_f32_16x16x32_bf16(Ah[g][0], Bh_[0], bias[g], 0, 0, 0);
      a = __builtin_amdgcn_mfma_f32_16x16x32_bf16(Ah[g][1], Bh_[1], a, 0, 0, 0);
      a = __builtin_amdgcn_mfma_f32_16x16x32_bf16(Ah[g][2], Bh_[2], a, 0, 0, 0);
      a = __builtin_amdgcn_mfma_f32_16x16x32_bf16(Ah[g][3], Bh_[3], a, 0, 0, 0);
      a = __builtin_amdgcn_mfma_f32_16x16x32_bf16(Axw[g][0], Bx0, a, 0, 0, 0);
      a = __builtin_amdgcn_mfma_f32_16x16x32_bf16(Axw[g][1], Bx1, a, 0, 0, 0);
      const float a01 = s0 ? a[1] : a[0];
      const float a23 = s0 ? a[3] : a[2];
      const float v = s1 ? a23 : a01;
      gact[g] = (g == 2) ? tanh_fast(v) : sigm(v);
      if (g == 2) {             // i,f,g ready: fold cell update under o-chain
        cc = gact[1] * cc + gact[0] * gact[2];
        tcc = tanh_fast(cc);
      }
    }

    // ---- short exposed tail ----
    hv = gact[3] * tcc;
    hbuf[(hcur ^ (4 * HSTR)) + br * HSTR + hcol] = f2bf(hv);
    LDS_BARRIER();   // the ONE barrier: h produced -> consumed next step
  }

  // ==================== fused epilogue (R11, unchanged) ====================
  // stage h_f (fwd half) and x_last for the backward one-step cell
  fst[br * 256 + hcol] = hv;
  {
    const int xrow = tid / DD;
    const int xd   = tid - xrow * DD;
    if (tid < CHUNK * DD)
      xl[xrow * 64 + xd] = X[((size_t)(b0 + xrow) * TT + (TT - 1)) * DD + xd];
  }
  __syncthreads();

  // backward gate pre-activations, fp32: thread n covers gate-row n for all
  // 4 batches; x_last broadcast from LDS
  {
    const int n = tid;                       // 0..511
    const float* wr = Wih_b + (size_t)n * DD;
    const float bb2 = bih_b[n] + bhh_b[n];
    float a0 = bb2, a1 = bb2, a2 = bb2, a3 = bb2;
    for (int k = 0; k < DD; ++k) {
      const float w = wr[k];
      a0 += w * xl[0 * 64 + k];
      a1 += w * xl[1 * 64 + k];
      a2 += w * xl[2 * 64 + k];
      a3 += w * xl[3 * 64 + k];
    }
    glb[0 * 512 + n] = a0;
    glb[1 * 512 + n] = a1;
    glb[2 * 512 + n] = a2;
    glb[3 * 512 + n] = a3;
  }
  __syncthreads();

  // backward cell (f*c0 = 0): h_b = o * tanh(i*g)
  {
    const int b = tid >> 7, j = tid & 127;   // 4 b x 128 j = 512 threads
    const float iv = sigm(glb[b * 512 + j]);
    const float gv = tanh_fast(glb[b * 512 + 256 + j]);
    const float ov = sigm(glb[b * 512 + 384 + j]);
    fst[b * 256 + 128 + j] = ov * tanh_fast(iv * gv);
  }
  __syncthreads();

  // full FC (+ bias) on [h_f ; h_b]
  if (tid < CHUNK * 14) {
    const int rr = tid / 14, o = tid - rr * 14;
    const float* wr = Wfc + (size_t)o * (2 * HH);
    float acc = bfc[o];
#pragma unroll 16
    for (int k = 0; k < 2 * HH; ++k) acc += wr[k] * fst[rr * 256 + k];
    out[(size_t)(b0 + rr) * 14 + o] = acc;
  }
}

extern "C" void kernel_launch(void* const* d_in, const int* in_sizes, int n_in,
                              void* d_out, int out_size, void* d_ws, size_t ws_size,
                              hipStream_t stream) {
  const float* X     = (const float*)d_in[0];
  const float* Wih_f = (const float*)d_in[1];
  const float* Whh_f = (const float*)d_in[2];
  const float* bih_f = (const float*)d_in[3];
  const float* bhh_f = (const float*)d_in[4];
  const float* Wih_b = (const float*)d_in[5];
  // d_in[6] = W_hh_b: unused (backward dir needs only one step from zero state)
  const float* bih_b = (const float*)d_in[7];
  const float* bhh_b = (const float*)d_in[8];
  const float* Wfc   = (const float*)d_in[9];
  const float* bfc   = (const float*)d_in[10];
  float* out = (float*)d_out;

  bilstm_fused_kernel<<<BB / CHUNK, 512, 0, stream>>>(
      X, Wih_f, Whh_f, bih_f, bhh_f, Wih_b, bih_b, bhh_b, Wfc, bfc, out);
}

// Round 8
// 273.552 us; speedup vs baseline: 1.2564x; 1.2564x over previous
//
#include <hip/hip_runtime.h>

typedef __attribute__((ext_vector_type(8))) short bf16x8;
typedef __attribute__((ext_vector_type(4))) float f32x4;

#define BB 1024
#define TT 256
#define DD 63
#define HH 128
#define CHUNK 4    // 4 batch rows/block, grid 256 = 1 block/CU
#define HSTR 160   // shorts; 80 dwords ≡ 16 (mod 32): broadcast b128 reads exactly 2-way (free)
#define XSTR 96    // shorts; 48 dwords ≡ 16 (mod 32)

// Barrier that drains only LDS (lgkmcnt), NOT outstanding global loads.
#define LDS_BARRIER() asm volatile("s_waitcnt lgkmcnt(0)\n\ts_barrier" ::: "memory")

__device__ __forceinline__ short f2bf(float f) {
  unsigned u = __builtin_bit_cast(unsigned, f);
  u = (u + 0x7FFFu + ((u >> 16) & 1u)) >> 16;   // RNE
  return (short)u;
}
__device__ __forceinline__ float sigm(float x) {
  return __builtin_amdgcn_rcpf(1.f + __expf(-x));
}
__device__ __forceinline__ float tanh_fast(float x) {
  float e = __expf(2.f * x);
  return 1.f - 2.f * __builtin_amdgcn_rcpf(e + 1.f);
}

// R18 = R11 (best measured, 207.5us) with the gate computation SOFTWARE-
// PIPELINED so activations trail their chain by one full chain:
//   R11/R10's per-gate stagger put act(g) BEFORE chain(g+1) in program
//   order; act(g) data-depends on chain(g)'s LAST MFMA, and waves issue
//   IN ORDER -> the wave stalls ~6 MFMA latencies per gate and chain(g+1)
//   cannot issue past the stall. Measured step = exact serial sum
//   931(MFMA) + 780(VALU) + 233(barrier/LDS) = 1944 cyc — no overlap.
//   New order: chain0; chain1; act0a; chain2; act0b,act1a; chain3;
//   act1b,act2,cell,act3 — every act dependence is >=1 chain old at issue,
//   so VALU slides under the MFMA issue window (~400 spare slots/wave).
// Operands, operand order, and formulas UNCHANGED -> bit-identical output.
// R17 post-mortem: global-direct x regressed (288us) — 32 scattered 16B
// VMEM/step/CU put TA/L1 in the loop; x stays in LDS (R11 path).
// Kept: launch_bounds(512,2) (R4); grid=256 = 1 block/CU (R5); HSTR=160/
// XSTR=96 (R7); one lgkm-only barrier/step (R8); fused epilogue (R11).
__global__ __launch_bounds__(512, 2)
void bilstm_fused_kernel(const float* __restrict__ X,
                         const float* __restrict__ Wih,
                         const float* __restrict__ Whh,
                         const float* __restrict__ bih,
                         const float* __restrict__ bhh,
                         const float* __restrict__ Wih_b,
                         const float* __restrict__ bih_b,
                         const float* __restrict__ bhh_b,
                         const float* __restrict__ Wfc,
                         const float* __restrict__ bfc,
                         float* __restrict__ out) {
  __shared__ __align__(16) short hbuf[2 * 4 * HSTR];   // h^T (bf16), rows=batch 0..3, dbuf
  __shared__ __align__(16) short xbuf[2 * 4 * XSTR];   // x^T (bf16), rows=batch 0..3, 2 slots
  __shared__ __align__(16) float fst[4 * 256];         // epilogue [h_f ; h_b] per batch
  __shared__ __align__(16) float xl[4 * 64];           // x_last fp32, pad 64
  __shared__ __align__(16) float glb[4 * 512];         // bwd gate pre-acts [b][n]

  const int tid  = threadIdx.x;
  const int wave = tid >> 6;
  const int lane = tid & 63;
  const int quad = lane >> 4;
  const int l15  = lane & 15;
  const int b0   = blockIdx.x * CHUNK;
  const int br   = l15 & 3;        // this lane's batch row
  // duplicate-group index p = l15>>2 selects which acc register is valid

  // ---- register-resident W fragments as MFMA A operands ----
  bf16x8 Ah[4][4];   // [gate][kstep], W_hh
  bf16x8 Axw[4][2];  // [gate][kstep], W_ih (K padded 63->64)
  f32x4  bias[4];    // bias per acc reg q: col = wave*16 + quad*4 + q
#pragma unroll
  for (int g = 0; g < 4; ++g) {
    const int n = g * 128 + wave * 16 + l15;
    const float* wr = Whh + (size_t)n * HH;
#pragma unroll
    for (int ks = 0; ks < 4; ++ks) {
      const int k0 = ks * 32 + quad * 8;
      f32x4 w0 = *(const f32x4*)(wr + k0);
      f32x4 w1 = *(const f32x4*)(wr + k0 + 4);
      bf16x8 v;
#pragma unroll
      for (int jj = 0; jj < 4; ++jj) { v[jj] = f2bf(w0[jj]); v[4 + jj] = f2bf(w1[jj]); }
      Ah[g][ks] = v;
    }
    const float* xr = Wih + (size_t)n * DD;
#pragma unroll
    for (int ks = 0; ks < 2; ++ks) {
      const int k0 = ks * 32 + quad * 8;
      bf16x8 v;
#pragma unroll
      for (int jj = 0; jj < 8; ++jj) {
        const int k = k0 + jj;
        v[jj] = (k < DD) ? f2bf(xr[k]) : (short)0;
      }
      Axw[g][ks] = v;
    }
    const int cb = g * 128 + wave * 16 + quad * 4;
    f32x4 b1 = *(const f32x4*)&bih[cb];
    f32x4 b2 = *(const f32x4*)&bhh[cb];
    bias[g] = b1 + b2;
  }

  // zero h buffers (h(0)=0); x pad columns zeroed once (both slots)
  for (int i = tid; i < 2 * 4 * HSTR; i += 512) hbuf[i] = 0;
  if (tid >= CHUNK * DD && tid < 256) {
    const int rr = tid & 3;
    xbuf[rr * XSTR + DD] = 0;
    xbuf[4 * XSTR + rr * XSTR + DD] = 0;
  }

  // x staging (R8 mapping): 4 rows x 63 cols = 252 threads, distance-2
  const int xrow = tid / DD;
  const int xd   = tid - xrow * DD;
  const bool xthr = (tid < CHUNK * DD);
  const float* xptr = X + ((size_t)(b0 + xrow) * TT) * DD + xd;
  float xv_pend = 0.f;
  if (xthr) {
    xbuf[xrow * XSTR + xd] = f2bf(xptr[0]);   // slot 0 = x(0)
    xv_pend = xptr[DD];                        // x(1)
    xptr += 2 * DD;
  }
  __syncthreads();

  float cc = 0.f, hv = 0.f;   // ONE element per lane: (batch=br, col=wave*16+quad*4+p)
  const int hcol = wave * 16 + quad * 4 + (l15 >> 2);
  const bool s0 = (l15 & 4) != 0;
  const bool s1 = (l15 & 8) != 0;

#define MF(Aop, Bop, Cop) __builtin_amdgcn_mfma_f32_16x16x32_bf16(Aop, Bop, Cop, 0, 0, 0)
#define CHAIN6(Aacc, g_)                       \
  do {                                         \
    Aacc = MF(Ah[g_][0], Bh_[0], bias[g_]);    \
    Aacc = MF(Ah[g_][1], Bh_[1], Aacc);        \
    Aacc = MF(Ah[g_][2], Bh_[2], Aacc);        \
    Aacc = MF(Ah[g_][3], Bh_[3], Aacc);        \
    Aacc = MF(Axw[g_][0], Bx0, Aacc);          \
    Aacc = MF(Axw[g_][1], Bx1, Aacc);          \
  } while (0)
#define SEL(Aacc) (s1 ? (s0 ? Aacc[3] : Aacc[2]) : (s0 ? Aacc[1] : Aacc[0]))

  for (int t = 0; t < TT; ++t) {
    const int xcur = (t & 1) * (4 * XSTR);
    const int hcur = (t & 1) * (4 * HSTR);

    // issue x(t+2) early; stays in flight across the lgkm-only barrier
    float xv_new = 0.f;
    const bool pf2 = xthr && (t + 2 < TT);
    if (pf2) { xv_new = *xptr; xptr += DD; }

    // B-fragments: row br (l15&3) -> 4-way same-address broadcast, 2-way banks
    bf16x8 Bh_[4], Bx0, Bx1;
#pragma unroll
    for (int ks = 0; ks < 4; ++ks)
      Bh_[ks] = *(const bf16x8*)&hbuf[hcur + br * HSTR + ks * 32 + quad * 8];
    Bx0 = *(const bf16x8*)&xbuf[xcur + br * XSTR + quad * 8];
    Bx1 = *(const bf16x8*)&xbuf[xcur + br * XSTR + 32 + quad * 8];

    // ---- software-pipelined gates: act(g) issues AFTER chain(g+1), so no
    //      act ever stalls the in-order wave before an independent chain ----
    f32x4 A0, A1, A2, A3;
    CHAIN6(A0, 0);                 // i-gate chain
    CHAIN6(A1, 1);                 // f-gate chain (independent, issues back-to-back)
    const float v0 = SEL(A0);      // act0 front half (A0 long done by now)
    const float e0 = __expf(-v0);
    CHAIN6(A2, 2);                 // g-gate chain
    const float gi = __builtin_amdgcn_rcpf(1.f + e0);       // act0 finish
    const float v1 = SEL(A1);                               // act1 front half
    const float e1 = __expf(-v1);
    CHAIN6(A3, 3);                 // o-gate chain
    const float gf = __builtin_amdgcn_rcpf(1.f + e1);       // act1 finish
    const float v2 = SEL(A2);                               // act2 (tanh)
    const float eg = __expf(2.f * v2);
    const float gg = 1.f - 2.f * __builtin_amdgcn_rcpf(eg + 1.f);
    cc = gf * cc + gi * gg;                                  // cell update
    const float tcc = tanh_fast(cc);
    const float v3 = SEL(A3);                                // act3 (o)
    const float go = sigm(v3);
    hv = go * tcc;
    hbuf[(hcur ^ (4 * HSTR)) + br * HSTR + hcol] = f2bf(hv);

    if (xthr && (t + 1 < TT))
      xbuf[(xcur ^ (4 * XSTR)) + xrow * XSTR + xd] = f2bf(xv_pend);
    xv_pend = xv_new;
    LDS_BARRIER();   // the ONE barrier: h/x produced -> consumed next step
  }

#undef MF
#undef CHAIN6
#undef SEL

  // ==================== fused epilogue (R11, unchanged) ====================
  // stage h_f (fwd half) and x_last for the backward one-step cell
  fst[br * 256 + hcol] = hv;
  if (xthr)
    xl[xrow * 64 + xd] = X[((size_t)(b0 + xrow) * TT + (TT - 1)) * DD + xd];
  __syncthreads();

  // backward gate pre-activations, fp32 (identical math to old bwd kernel):
  // thread n covers gate-row n for all 4 batches; x_last broadcast from LDS
  {
    const int n = tid;                       // 0..511
    const float* wr = Wih_b + (size_t)n * DD;
    const float bb2 = bih_b[n] + bhh_b[n];
    float a0 = bb2, a1 = bb2, a2 = bb2, a3 = bb2;
    for (int k = 0; k < DD; ++k) {
      const float w = wr[k];
      a0 += w * xl[0 * 64 + k];
      a1 += w * xl[1 * 64 + k];
      a2 += w * xl[2 * 64 + k];
      a3 += w * xl[3 * 64 + k];
    }
    glb[0 * 512 + n] = a0;
    glb[1 * 512 + n] = a1;
    glb[2 * 512 + n] = a2;
    glb[3 * 512 + n] = a3;
  }
  __syncthreads();

  // backward cell (f*c0 = 0): h_b = o * tanh(i*g)
  {
    const int b = tid >> 7, j = tid & 127;   // 4 b x 128 j = 512 threads
    const float iv = sigm(glb[b * 512 + j]);
    const float gv = tanh_fast(glb[b * 512 + 256 + j]);
    const float ov = sigm(glb[b * 512 + 384 + j]);
    fst[b * 256 + 128 + j] = ov * tanh_fast(iv * gv);
  }
  __syncthreads();

  // full FC (+ bias) on [h_f ; h_b]
  if (tid < CHUNK * 14) {
    const int rr = tid / 14, o = tid - rr * 14;
    const float* wr = Wfc + (size_t)o * (2 * HH);
    float acc = bfc[o];
#pragma unroll 16
    for (int k = 0; k < 2 * HH; ++k) acc += wr[k] * fst[rr * 256 + k];
    out[(size_t)(b0 + rr) * 14 + o] = acc;
  }
}

extern "C" void kernel_launch(void* const* d_in, const int* in_sizes, int n_in,
                              void* d_out, int out_size, void* d_ws, size_t ws_size,
                              hipStream_t stream) {
  const float* X     = (const float*)d_in[0];
  const float* Wih_f = (const float*)d_in[1];
  const float* Whh_f = (const float*)d_in[2];
  const float* bih_f = (const float*)d_in[3];
  const float* bhh_f = (const float*)d_in[4];
  const float* Wih_b = (const float*)d_in[5];
  // d_in[6] = W_hh_b: unused (backward dir needs only one step from zero state)
  const float* bih_b = (const float*)d_in[7];
  const float* bhh_b = (const float*)d_in[8];
  const float* Wfc   = (const float*)d_in[9];
  const float* bfc   = (const float*)d_in[10];
  float* out = (float*)d_out;

  bilstm_fused_kernel<<<BB / CHUNK, 512, 0, stream>>>(
      X, Wih_f, Whh_f, bih_f, bhh_f, Wih_b, bih_b, bhh_b, Wfc, bfc, out);
}

// Round 12
// 271.826 us; speedup vs baseline: 1.2644x; 1.0063x over previous
//
#include <hip/hip_runtime.h>

typedef __attribute__((ext_vector_type(8))) short bf16x8;
typedef __attribute__((ext_vector_type(4))) float f32x4;

#define BB 1024
#define TT 256
#define DD 63
#define HH 128
#define CHUNK 4    // 4 batch rows/block, grid 256 = 1 block/CU
#define HSTR 160   // shorts; 80 dwords ≡ 16 (mod 32): broadcast b128 reads exactly 2-way (free)
#define XSTR 96    // shorts; 48 dwords ≡ 16 (mod 32)

__device__ __forceinline__ short f2bf(float f) {
  unsigned u = __builtin_bit_cast(unsigned, f);
  u = (u + 0x7FFFu + ((u >> 16) & 1u)) >> 16;   // RNE
  return (short)u;
}
__device__ __forceinline__ float sigm(float x) {
  return __builtin_amdgcn_rcpf(1.f + __expf(-x));
}
__device__ __forceinline__ float tanh_fast(float x) {
  float e = __expf(2.f * x);
  return 1.f - 2.f * __builtin_amdgcn_rcpf(e + 1.f);
}

// R20 = R19 (round-robin MFMA interleave) with the hand-rolled inline-asm
// barrier REPLACED by intrinsic __syncthreads():
//   R19 passed the first correctness check but DIVERGED post-timing
//   (absmax 0.21, intermittent) — a race/ordering hazard exposed by the
//   rescheduled step. Rule-#18 hazard class: an inline-asm
//   "s_waitcnt lgkmcnt(0); s_barrier" with only a "memory" clobber does NOT
//   order register-only MFMA/VALU; the compiler may move them across it.
//   __syncthreads() is modeled correctly by the scheduler. The old barrier's
//   advantage (x-prefetch loads in flight across it) is moot: the load is
//   consumed by a ds_write at the end of the SAME step (~1000+ cyc after
//   issue, L2-resident) -> the extra vmcnt(0) drain is ~free.
// Interleave hypothesis (unchanged, still unmeasured): R11/R18 counters give
// 830 cyc MFMA-busy / 48 wave-MFMAs = 17.3 cyc/MFMA = dependent-latency
// cadence. Round-robin g0k0,g1k0,g2k0,g3k0,g0k1,... puts each MFMA's C-dep
// 4 instructions back >= latency -> issue-rate MFMA phase (408 -> ~120
// cyc/wave). Operands & per-chain accumulation order unchanged -> output
// bit-identical to R11/R18.
// (Resubmitted unchanged after R11's GPUAcquisitionTimeout — never measured.)
// Kept: launch_bounds(512,2) (R4); grid=256 = 1 block/CU (R5); HSTR=160/
// XSTR=96 (R7); fused epilogue (R11); x in LDS (R17: global-direct x loses).
__global__ __launch_bounds__(512, 2)
void bilstm_fused_kernel(const float* __restrict__ X,
                         const float* __restrict__ Wih,
                         const float* __restrict__ Whh,
                         const float* __restrict__ bih,
                         const float* __restrict__ bhh,
                         const float* __restrict__ Wih_b,
                         const float* __restrict__ bih_b,
                         const float* __restrict__ bhh_b,
                         const float* __restrict__ Wfc,
                         const float* __restrict__ bfc,
                         float* __restrict__ out) {
  __shared__ __align__(16) short hbuf[2 * 4 * HSTR];   // h^T (bf16), rows=batch 0..3, dbuf
  __shared__ __align__(16) short xbuf[2 * 4 * XSTR];   // x^T (bf16), rows=batch 0..3, 2 slots
  __shared__ __align__(16) float fst[4 * 256];         // epilogue [h_f ; h_b] per batch
  __shared__ __align__(16) float xl[4 * 64];           // x_last fp32, pad 64
  __shared__ __align__(16) float glb[4 * 512];         // bwd gate pre-acts [b][n]

  const int tid  = threadIdx.x;
  const int wave = tid >> 6;
  const int lane = tid & 63;
  const int quad = lane >> 4;
  const int l15  = lane & 15;
  const int b0   = blockIdx.x * CHUNK;
  const int br   = l15 & 3;        // this lane's batch row
  // duplicate-group index p = l15>>2 selects which acc register is valid

  // ---- register-resident W fragments as MFMA A operands ----
  bf16x8 Ah[4][4];   // [gate][kstep], W_hh
  bf16x8 Axw[4][2];  // [gate][kstep], W_ih (K padded 63->64)
  f32x4  bias[4];    // bias per acc reg q: col = wave*16 + quad*4 + q
#pragma unroll
  for (int g = 0; g < 4; ++g) {
    const int n = g * 128 + wave * 16 + l15;
    const float* wr = Whh + (size_t)n * HH;
#pragma unroll
    for (int ks = 0; ks < 4; ++ks) {
      const int k0 = ks * 32 + quad * 8;
      f32x4 w0 = *(const f32x4*)(wr + k0);
      f32x4 w1 = *(const f32x4*)(wr + k0 + 4);
      bf16x8 v;
#pragma unroll
      for (int jj = 0; jj < 4; ++jj) { v[jj] = f2bf(w0[jj]); v[4 + jj] = f2bf(w1[jj]); }
      Ah[g][ks] = v;
    }
    const float* xr = Wih + (size_t)n * DD;
#pragma unroll
    for (int ks = 0; ks < 2; ++ks) {
      const int k0 = ks * 32 + quad * 8;
      bf16x8 v;
#pragma unroll
      for (int jj = 0; jj < 8; ++jj) {
        const int k = k0 + jj;
        v[jj] = (k < DD) ? f2bf(xr[k]) : (short)0;
      }
      Axw[g][ks] = v;
    }
    const int cb = g * 128 + wave * 16 + quad * 4;
    f32x4 b1 = *(const f32x4*)&bih[cb];
    f32x4 b2 = *(const f32x4*)&bhh[cb];
    bias[g] = b1 + b2;
  }

  // zero h buffers (h(0)=0); x pad columns zeroed once (both slots)
  for (int i = tid; i < 2 * 4 * HSTR; i += 512) hbuf[i] = 0;
  if (tid >= CHUNK * DD && tid < 256) {
    const int rr = tid & 3;
    xbuf[rr * XSTR + DD] = 0;
    xbuf[4 * XSTR + rr * XSTR + DD] = 0;
  }

  // x staging (R8 mapping): 4 rows x 63 cols = 252 threads, distance-2
  const int xrow = tid / DD;
  const int xd   = tid - xrow * DD;
  const bool xthr = (tid < CHUNK * DD);
  const float* xptr = X + ((size_t)(b0 + xrow) * TT) * DD + xd;
  float xv_pend = 0.f;
  if (xthr) {
    xbuf[xrow * XSTR + xd] = f2bf(xptr[0]);   // slot 0 = x(0)
    xv_pend = xptr[DD];                        // x(1)
    xptr += 2 * DD;
  }
  __syncthreads();

  float cc = 0.f, hv = 0.f;   // ONE element per lane: (batch=br, col=wave*16+quad*4+p)
  const int hcol = wave * 16 + quad * 4 + (l15 >> 2);
  const bool s0 = (l15 & 4) != 0;
  const bool s1 = (l15 & 8) != 0;

#define MF(Aop, Bop, Cop) __builtin_amdgcn_mfma_f32_16x16x32_bf16(Aop, Bop, Cop, 0, 0, 0)
#define SEL(Aacc) (s1 ? (s0 ? Aacc[3] : Aacc[2]) : (s0 ? Aacc[1] : Aacc[0]))

  for (int t = 0; t < TT; ++t) {
    const int xcur = (t & 1) * (4 * XSTR);
    const int hcur = (t & 1) * (4 * HSTR);

    // issue x(t+2) early (consumed by the ds_write at the end of this step)
    float xv_new = 0.f;
    const bool pf2 = xthr && (t + 2 < TT);
    if (pf2) { xv_new = *xptr; xptr += DD; }

    // B-fragments: row br (l15&3) -> 4-way same-address broadcast, 2-way banks
    bf16x8 Bh_[4], Bx0, Bx1;
#pragma unroll
    for (int ks = 0; ks < 4; ++ks)
      Bh_[ks] = *(const bf16x8*)&hbuf[hcur + br * HSTR + ks * 32 + quad * 8];
    Bx0 = *(const bf16x8*)&xbuf[xcur + br * XSTR + quad * 8];
    Bx1 = *(const bf16x8*)&xbuf[xcur + br * XSTR + 32 + quad * 8];

    // ---- ROUND-ROBIN interleaved chains: each MFMA's C-dependence is 4
    //      instructions back (>= dependent latency) -> issue-rate MFMA ----
    f32x4 A0, A1, A2, A3;
    A0 = MF(Ah[0][0], Bh_[0], bias[0]);
    A1 = MF(Ah[1][0], Bh_[0], bias[1]);
    A2 = MF(Ah[2][0], Bh_[0], bias[2]);
    A3 = MF(Ah[3][0], Bh_[0], bias[3]);
    A0 = MF(Ah[0][1], Bh_[1], A0);
    A1 = MF(Ah[1][1], Bh_[1], A1);
    A2 = MF(Ah[2][1], Bh_[1], A2);
    A3 = MF(Ah[3][1], Bh_[1], A3);
    A0 = MF(Ah[0][2], Bh_[2], A0);
    A1 = MF(Ah[1][2], Bh_[2], A1);
    A2 = MF(Ah[2][2], Bh_[2], A2);
    A3 = MF(Ah[3][2], Bh_[2], A3);
    A0 = MF(Ah[0][3], Bh_[3], A0);
    A1 = MF(Ah[1][3], Bh_[3], A1);
    A2 = MF(Ah[2][3], Bh_[3], A2);
    A3 = MF(Ah[3][3], Bh_[3], A3);
    A0 = MF(Axw[0][0], Bx0, A0);
    A1 = MF(Axw[1][0], Bx0, A1);
    A2 = MF(Axw[2][0], Bx0, A2);
    A3 = MF(Axw[3][0], Bx0, A3);
    A0 = MF(Axw[0][1], Bx1, A0);
    A1 = MF(Axw[1][1], Bx1, A1);
    A2 = MF(Axw[2][1], Bx1, A2);
    A3 = MF(Axw[3][1], Bx1, A3);

    // ---- activations (gate 0 finished ~4 MFMA slots ago; tail is short) ----
    const float v0 = SEL(A0);
    const float gi = sigm(v0);
    const float v1 = SEL(A1);
    const float gf = sigm(v1);
    const float v2 = SEL(A2);
    const float gg = tanh_fast(v2);
    cc = gf * cc + gi * gg;
    const float tcc = tanh_fast(cc);
    const float v3 = SEL(A3);
    const float go = sigm(v3);
    hv = go * tcc;
    hbuf[(hcur ^ (4 * HSTR)) + br * HSTR + hcol] = f2bf(hv);

    if (xthr && (t + 1 < TT))
      xbuf[(xcur ^ (4 * XSTR)) + xrow * XSTR + xd] = f2bf(xv_pend);
    xv_pend = xv_new;
    __syncthreads();   // intrinsic barrier: h/x produced -> consumed next step
  }

#undef MF
#undef SEL

  // ==================== fused epilogue (R11, unchanged) ====================
  // stage h_f (fwd half) and x_last for the backward one-step cell
  fst[br * 256 + hcol] = hv;
  if (xthr)
    xl[xrow * 64 + xd] = X[((size_t)(b0 + xrow) * TT + (TT - 1)) * DD + xd];
  __syncthreads();

  // backward gate pre-activations, fp32 (identical math to old bwd kernel):
  // thread n covers gate-row n for all 4 batches; x_last broadcast from LDS
  {
    const int n = tid;                       // 0..511
    const float* wr = Wih_b + (size_t)n * DD;
    const float bb2 = bih_b[n] + bhh_b[n];
    float a0 = bb2, a1 = bb2, a2 = bb2, a3 = bb2;
    for (int k = 0; k < DD; ++k) {
      const float w = wr[k];
      a0 += w * xl[0 * 64 + k];
      a1 += w * xl[1 * 64 + k];
      a2 += w * xl[2 * 64 + k];
      a3 += w * xl[3 * 64 + k];
    }
    glb[0 * 512 + n] = a0;
    glb[1 * 512 + n] = a1;
    glb[2 * 512 + n] = a2;
    glb[3 * 512 + n] = a3;
  }
  __syncthreads();

  // backward cell (f*c0 = 0): h_b = o * tanh(i*g)
  {
    const int b = tid >> 7, j = tid & 127;   // 4 b x 128 j = 512 threads
    const float iv = sigm(glb[b * 512 + j]);
    const float gv = tanh_fast(glb[b * 512 + 256 + j]);
    const float ov = sigm(glb[b * 512 + 384 + j]);
    fst[b * 256 + 128 + j] = ov * tanh_fast(iv * gv);
  }
  __syncthreads();

  // full FC (+ bias) on [h_f ; h_b]
  if (tid < CHUNK * 14) {
    const int rr = tid / 14, o = tid - rr * 14;
    const float* wr = Wfc + (size_t)o * (2 * HH);
    float acc = bfc[o];
#pragma unroll 16
    for (int k = 0; k < 2 * HH; ++k) acc += wr[k] * fst[rr * 256 + k];
    out[(size_t)(b0 + rr) * 14 + o] = acc;
  }
}

extern "C" void kernel_launch(void* const* d_in, const int* in_sizes, int n_in,
                              void* d_out, int out_size, void* d_ws, size_t ws_size,
                              hipStream_t stream) {
  const float* X     = (const float*)d_in[0];
  const float* Wih_f = (const float*)d_in[1];
  const float* Whh_f = (const float*)d_in[2];
  const float* bih_f = (const float*)d_in[3];
  const float* bhh_f = (const float*)d_in[4];
  const float* Wih_b = (const float*)d_in[5];
  // d_in[6] = W_hh_b: unused (backward dir needs only one step from zero state)
  const float* bih_b = (const float*)d_in[7];
  const float* bhh_b = (const float*)d_in[8];
  const float* Wfc   = (const float*)d_in[9];
  const float* bfc   = (const float*)d_in[10];
  float* out = (float*)d_out;

  bilstm_fused_kernel<<<BB / CHUNK, 512, 0, stream>>>(
      X, Wih_f, Whh_f, bih_f, bhh_f, Wih_b, bih_b, bhh_b, Wfc, bfc, out);
}